// Round 2
// baseline (903.007 us; speedup 1.0000x reference)
//
#include <hip/hip_runtime.h>
#include <math.h>

#define N_PRED   8192
#define N_CLS    150
#define N_BATCH  16
#define T_DIM    (N_BATCH * N_CLS)          // 2400
#define NPIX     (N_BATCH * 1024 * 1024)    // 16777216
#define PIX_SHIFT 20                         // pixels per batch image = 2^20
#define NBINS    (N_PRED * T_DIM)            // 19,660,800 pair bins
#define NOV_WORDS (NBINS / 2)                // u16-packed, 2 bins per u32 word
#define NOV_BYTES ((size_t)NOV_WORDS * 4)    // 39,321,600
#define NP_BYTES  ((size_t)N_PRED * 4)       // 32,768
#define NT_BYTES  ((size_t)T_DIM * 4)        // 9,600
#define OUT_BYTES ((size_t)N_PRED * N_CLS * 4) // 4,915,200
#define WS_TOTAL  (NOV_BYTES + NP_BYTES + NT_BYTES + OUT_BYTES)

// ---------------- Pass 1: histograms ----------------
// n_ov packed u16 (2 bins / u32 word); n_p, n_t privatized in LDS per block.
__global__ __launch_bounds__(256) void hist_kernel(
    const int* __restrict__ predseg, const int* __restrict__ targetseg,
    unsigned* __restrict__ n_ov, unsigned* __restrict__ n_p, unsigned* __restrict__ n_t) {
    __shared__ unsigned s_np[N_PRED];   // 32 KB
    __shared__ unsigned s_nt[T_DIM];    // 9.6 KB
    for (int j = threadIdx.x; j < N_PRED; j += 256) s_np[j] = 0u;
    for (int j = threadIdx.x; j < T_DIM;  j += 256) s_nt[j] = 0u;
    __syncthreads();

    int idx    = blockIdx.x * 256 + threadIdx.x;
    int stride = gridDim.x * 256;
    const int nq = NPIX / 4;
    for (int i = idx; i < nq; i += stride) {
        int4 pv = ((const int4*)predseg)[i];
        int4 cv = ((const int4*)targetseg)[i];
        // all 4 pixels of an aligned int4 share the same batch index
        int tb = ((i * 4) >> PIX_SHIFT) * N_CLS;
        int t0 = tb + cv.x, t1 = tb + cv.y, t2 = tb + cv.z, t3 = tb + cv.w;
        int pair0 = pv.x * T_DIM + t0;
        int pair1 = pv.y * T_DIM + t1;
        int pair2 = pv.z * T_DIM + t2;
        int pair3 = pv.w * T_DIM + t3;
        atomicAdd(&n_ov[pair0 >> 1], (pair0 & 1) ? 0x10000u : 1u);
        atomicAdd(&n_ov[pair1 >> 1], (pair1 & 1) ? 0x10000u : 1u);
        atomicAdd(&n_ov[pair2 >> 1], (pair2 & 1) ? 0x10000u : 1u);
        atomicAdd(&n_ov[pair3 >> 1], (pair3 & 1) ? 0x10000u : 1u);
        atomicAdd(&s_np[pv.x], 1u); atomicAdd(&s_np[pv.y], 1u);
        atomicAdd(&s_np[pv.z], 1u); atomicAdd(&s_np[pv.w], 1u);
        atomicAdd(&s_nt[t0], 1u); atomicAdd(&s_nt[t1], 1u);
        atomicAdd(&s_nt[t2], 1u); atomicAdd(&s_nt[t3], 1u);
    }
    __syncthreads();
    for (int j = threadIdx.x; j < N_PRED; j += 256) { unsigned v = s_np[j]; if (v) atomicAdd(&n_p[j], v); }
    for (int j = threadIdx.x; j < T_DIM;  j += 256) { unsigned v = s_nt[j]; if (v) atomicAdd(&n_t[j], v); }
}

// ---------------- Pass 2: pair-bin sweep -> out[p][cls] ----------------
__global__ __launch_bounds__(256) void sweep_kernel(
    const unsigned* __restrict__ n_ov, const unsigned* __restrict__ n_p,
    const unsigned* __restrict__ n_t, float* __restrict__ out) {
    int idx    = blockIdx.x * 256 + threadIdx.x;
    int stride = gridDim.x * 256;
    const int nqw = NOV_WORDS / 4;          // uint4 = 4 words = 8 bins
    for (int i = idx; i < nqw; i += stride) {
        uint4 v = ((const uint4*)n_ov)[i];
        if ((v.x | v.y | v.z | v.w) == 0u) continue;
        int bin0 = i * 8;                    // 2400 % 8 == 0 -> same p for all 8
        int p  = bin0 / T_DIM;
        int t0 = bin0 - p * T_DIM;
        float np = (float)n_p[p];
        float* outrow = out + p * N_CLS;
        unsigned w4[4] = {v.x, v.y, v.z, v.w};
        #pragma unroll
        for (int j = 0; j < 8; ++j) {
            unsigned nov = (w4[j >> 1] >> ((j & 1) * 16)) & 0xFFFFu;
            if (!nov) continue;
            int t   = t0 + j;
            int cls = t % N_CLS;
            float f = (float)nov;
            atomicAdd(&outrow[cls], f / (np + (float)n_t[t] - f));
        }
    }
}

// ---------------- Pass 3: per-row focal CE, mean ----------------
__global__ __launch_bounds__(256) void loss_kernel(
    const float* __restrict__ pred, const float* __restrict__ outbuf,
    float* __restrict__ loss_out, float cnorm) {
    __shared__ float s_l[4];
    int row  = blockIdx.x * 4 + (threadIdx.x >> 6);
    int lane = threadIdx.x & 63;
    const float* pr   = pred   + (size_t)row * N_CLS;
    const float* orow = outbuf + (size_t)row * N_CLS;

    float pv[3], ov[3];
    float rowsum = 0.f, pmax = -INFINITY;
    #pragma unroll
    for (int k = 0; k < 3; ++k) {
        int c = lane + k * 64;
        bool ok = c < N_CLS;
        pv[k] = ok ? pr[c]   : -INFINITY;
        ov[k] = ok ? orow[c] : 0.f;
        rowsum += ov[k];
        pmax = fmaxf(pmax, pv[k]);
    }
    #pragma unroll
    for (int off = 32; off; off >>= 1) {
        rowsum += __shfl_xor(rowsum, off);
        pmax = fmaxf(pmax, __shfl_xor(pmax, off));
    }
    float sumexp = 0.f;
    #pragma unroll
    for (int k = 0; k < 3; ++k) {
        int c = lane + k * 64;
        if (c < N_CLS) sumexp += __expf(pv[k] - pmax);
    }
    #pragma unroll
    for (int off = 32; off; off >>= 1) sumexp += __shfl_xor(sumexp, off);
    float lse = __logf(sumexp) + pmax;      // logp[c] = pred[c] - lse

    float inv = 1.f / rowsum;
    float ce = 0.f, bestv = -INFINITY;
    int besti = 0;
    #pragma unroll
    for (int k = 0; k < 3; ++k) {
        int c = lane + k * 64;
        if (c >= N_CLS) continue;
        float tg = ov[k] * inv;
        if (c != 0) ce -= tg * (pv[k] - lse);   // cls_w[0] = 0
        if (tg > bestv) { bestv = tg; besti = c; }  // first max within lane
    }
    #pragma unroll
    for (int off = 32; off; off >>= 1) {
        ce += __shfl_xor(ce, off);
        float bv = __shfl_xor(bestv, off);
        int   bi = __shfl_xor(besti, off);
        if (bv > bestv || (bv == bestv && bi < besti)) { bestv = bv; besti = bi; }
    }
    if (lane == 0) {
        float ptv = __expf(pr[besti] - lse);    // softmax at argmax(target)
        float x  = 1.f - ptv;
        float x2 = x * x;
        s_l[threadIdx.x >> 6] = x2 * x2 * ce * cnorm;
    }
    __syncthreads();
    if (threadIdx.x == 0) {
        float s = s_l[0] + s_l[1] + s_l[2] + s_l[3];
        atomicAdd(loss_out, s * (1.0f / (float)N_PRED));
    }
}

// Host-side: reproduce _norm_factor(4.0) — trapezoid of (1-t^5)/(1-t), 1000 pts.
static float compute_cnorm() {
    const double eps = 1e-7, gamma = 4.0;
    double h = 0.0, prev_t = 0.0, prev_y = 1.0;   // y(0) = 1
    for (int i = 1; i < 1000; ++i) {
        double t = (double)i * (1.0 - eps) / 999.0;
        double y = (1.0 - pow(t, gamma + 1.0)) / (1.0 - t);
        h += 0.5 * (y + prev_y) * (t - prev_t);
        prev_t = t; prev_y = y;
    }
    return (float)((gamma + 1.0) / h);
}

extern "C" void kernel_launch(void* const* d_in, const int* in_sizes, int n_in,
                              void* d_out, int out_size, void* d_ws, size_t ws_size,
                              hipStream_t stream) {
    const float* pred     = (const float*)d_in[0];
    const int*   predseg  = (const int*)d_in[1];
    const int*   targetseg= (const int*)d_in[2];
    unsigned char* ws = (unsigned char*)d_ws;
    unsigned* n_ov = (unsigned*)ws;
    unsigned* n_p  = (unsigned*)(ws + NOV_BYTES);
    unsigned* n_t  = (unsigned*)(ws + NOV_BYTES + NP_BYTES);
    float*    outb = (float*)  (ws + NOV_BYTES + NP_BYTES + NT_BYTES);

    float cnorm = compute_cnorm();

    hipMemsetAsync(d_ws, 0, WS_TOTAL, stream);
    hipMemsetAsync(d_out, 0, sizeof(float) * (size_t)out_size, stream);

    hist_kernel <<<768,  256, 0, stream>>>(predseg, targetseg, n_ov, n_p, n_t);
    sweep_kernel<<<2048, 256, 0, stream>>>(n_ov, n_p, n_t, outb);
    loss_kernel <<<N_PRED / 4, 256, 0, stream>>>(pred, outb, (float*)d_out, cnorm);
}

// Round 3
// 141.664 us; speedup vs baseline: 6.3743x; 6.3743x over previous
//
#include <hip/hip_runtime.h>
#include <math.h>

#define N_PRED   8192
#define N_CLS    150
#define N_BATCH  16
#define T_DIM    (N_BATCH * N_CLS)          // 2400
#define NPIX     (N_BATCH * 1024 * 1024)    // 16777216
#define PIX_SHIFT 20                         // pixels per image = 2^20

#define STRIPE   16384                       // pixels per partition block
#define NBLK_A   (NPIX / STRIPE)             // 1024 (stripes never cross images)
#define NBUK     512                          // p-buckets of 16 consecutive p
#define P_PER_BUK 16

#define KEYS_BYTES ((size_t)NPIX * 2)               // 33,554,432  (u16 keys)
#define DIR_BYTES  ((size_t)NBLK_A * NBUK * 4)      // 2,097,152
#define NT_BYTES   ((size_t)T_DIM * 4)              // 9,600
#define OUT_BYTES  ((size_t)N_PRED * N_CLS * 4)     // 4,915,200

// ---------------- Pass A: block-local counting sort into p-buckets ----------------
__global__ __launch_bounds__(256) void partition_kernel(
    const int* __restrict__ predseg, const int* __restrict__ targetseg,
    unsigned short* __restrict__ keys, unsigned* __restrict__ dir,
    unsigned* __restrict__ g_nt) {
    __shared__ unsigned s_cnt[NBUK];
    __shared__ unsigned s_scanA[NBUK];
    __shared__ unsigned s_scanB[NBUK];
    __shared__ unsigned s_nt[N_CLS];
    __shared__ unsigned short s_keys[STRIPE];

    int tid = threadIdx.x;
    int blk = blockIdx.x;
    size_t base = (size_t)blk * STRIPE;
    int tbase = (int)(base >> PIX_SHIFT) * N_CLS;   // t = img*150 + cls, img uniform per stripe

    for (int i = tid; i < NBUK;  i += 256) s_cnt[i] = 0u;
    for (int i = tid; i < N_CLS; i += 256) s_nt[i] = 0u;
    __syncthreads();

    const int4* pv4 = (const int4*)(predseg   + base);
    const int4* cv4 = (const int4*)(targetseg + base);

    // phase 1: count buckets + per-image class histogram
    for (int i = tid; i < STRIPE / 4; i += 256) {
        int4 pv = pv4[i]; int4 cv = cv4[i];
        atomicAdd(&s_cnt[pv.x >> 4], 1u); atomicAdd(&s_cnt[pv.y >> 4], 1u);
        atomicAdd(&s_cnt[pv.z >> 4], 1u); atomicAdd(&s_cnt[pv.w >> 4], 1u);
        atomicAdd(&s_nt[cv.x], 1u); atomicAdd(&s_nt[cv.y], 1u);
        atomicAdd(&s_nt[cv.z], 1u); atomicAdd(&s_nt[cv.w], 1u);
    }
    __syncthreads();

    // flush n_t (150 atomics per block, 153K total)
    for (int i = tid; i < N_CLS; i += 256) {
        unsigned v = s_nt[i];
        if (v) atomicAdd(&g_nt[tbase + i], v);
    }

    // exclusive scan of 512 bucket counts (Hillis-Steele, ping-pong)
    unsigned* src = s_scanA;
    unsigned* dst = s_scanB;
    for (int i = tid; i < NBUK; i += 256) src[i] = s_cnt[i];
    __syncthreads();
    for (int d = 1; d < NBUK; d <<= 1) {
        for (int i = tid; i < NBUK; i += 256)
            dst[i] = src[i] + (i >= d ? src[i - d] : 0u);
        __syncthreads();
        unsigned* t = src; src = dst; dst = t;
    }
    // src = inclusive scan; dst becomes running offsets; write directory
    unsigned* run = dst;
    for (int i = tid; i < NBUK; i += 256) {
        unsigned excl = i ? src[i - 1] : 0u;
        run[i] = excl;
        dir[(size_t)blk * NBUK + i] = excl | (s_cnt[i] << 16);  // start|count, both <= 16384
    }
    __syncthreads();

    // phase 2: scatter keys into LDS grouped by bucket (re-read input, L2-hot)
    for (int i = tid; i < STRIPE / 4; i += 256) {
        int4 pv = pv4[i]; int4 cv = cv4[i];
        int p, c; unsigned slot;
        p = pv.x; c = cv.x; slot = atomicAdd(&run[p >> 4], 1u);
        s_keys[slot] = (unsigned short)(((p & 15) << 12) | (tbase + c));
        p = pv.y; c = cv.y; slot = atomicAdd(&run[p >> 4], 1u);
        s_keys[slot] = (unsigned short)(((p & 15) << 12) | (tbase + c));
        p = pv.z; c = cv.z; slot = atomicAdd(&run[p >> 4], 1u);
        s_keys[slot] = (unsigned short)(((p & 15) << 12) | (tbase + c));
        p = pv.w; c = cv.w; slot = atomicAdd(&run[p >> 4], 1u);
        s_keys[slot] = (unsigned short)(((p & 15) << 12) | (tbase + c));
    }
    __syncthreads();

    // phase 3: fully-coalesced store of the 32KB key block
    uint4* dstv = (uint4*)(keys + base);
    const uint4* srcv = (const uint4*)s_keys;
    for (int i = tid; i < (STRIPE * 2) / 16; i += 256) dstv[i] = srcv[i];
}

// ---------------- Pass B: per-bucket LDS histogram + sweep -> out[p][cls] ----------------
__global__ __launch_bounds__(512) void hist_sweep_kernel(
    const unsigned short* __restrict__ keys, const unsigned* __restrict__ dir,
    const unsigned* __restrict__ g_nt, float* __restrict__ outb) {
    __shared__ unsigned s_hist[P_PER_BUK * T_DIM / 2];   // 19200 words, u16-packed, 76.8KB
    __shared__ float s_np[P_PER_BUK];

    int tid = threadIdx.x;
    int q   = blockIdx.x;
    for (int i = tid; i < P_PER_BUK * T_DIM / 2; i += 512) s_hist[i] = 0u;
    __syncthreads();

    // each thread owns whole segments (keys contiguous -> L1 line reuse, 512 MLP streams)
    for (int s = tid; s < NBLK_A; s += 512) {
        unsigned d = dir[(size_t)s * NBUK + q];
        int start = (int)(d & 0xFFFFu);
        int cnt   = (int)(d >> 16);
        const unsigned short* kp = keys + (size_t)s * STRIPE + start;
        for (int j = 0; j < cnt; ++j) {
            unsigned k = kp[j];
            unsigned bin = (k >> 12) * T_DIM + (k & 4095u);
            atomicAdd(&s_hist[bin >> 1], (bin & 1u) ? 0x10000u : 1u);
        }
    }
    __syncthreads();

    // n_p[lp] = row sums of local histogram
    int wid = tid >> 6, lane = tid & 63;
    for (int r = wid; r < P_PER_BUK; r += 8) {
        unsigned sum = 0;
        for (int t = lane; t < T_DIM; t += 64) {
            unsigned bin = r * T_DIM + t;
            sum += (s_hist[bin >> 1] >> ((bin & 1u) * 16)) & 0xFFFFu;
        }
        #pragma unroll
        for (int off = 32; off; off >>= 1) sum += __shfl_xor(sum, off);
        if (lane == 0) s_np[r] = (float)sum;
    }
    __syncthreads();

    // sweep: out[p][cls] = sum_b n_ov/(n_p+n_t-n_ov); each (p,cls) owned here -> plain store
    for (int idx = tid; idx < P_PER_BUK * N_CLS; idx += 512) {
        int lp  = idx / N_CLS;
        int cls = idx - lp * N_CLS;
        float np = s_np[lp];
        float acc = 0.f;
        #pragma unroll
        for (int b = 0; b < N_BATCH; ++b) {
            int t = b * N_CLS + cls;
            unsigned bin = (unsigned)(lp * T_DIM + t);
            unsigned c = (s_hist[bin >> 1] >> ((bin & 1u) * 16)) & 0xFFFFu;
            if (c) {
                float f = (float)c;
                acc += f / (np + (float)g_nt[t] - f);
            }
        }
        outb[(size_t)(q * P_PER_BUK + lp) * N_CLS + cls] = acc;
    }
}

// ---------------- Pass C: per-row focal CE, mean ----------------
__global__ __launch_bounds__(256) void loss_kernel(
    const float* __restrict__ pred, const float* __restrict__ outbuf,
    float* __restrict__ loss_out, float cnorm) {
    __shared__ float s_l[4];
    int row  = blockIdx.x * 4 + (threadIdx.x >> 6);
    int lane = threadIdx.x & 63;
    const float* pr   = pred   + (size_t)row * N_CLS;
    const float* orow = outbuf + (size_t)row * N_CLS;

    float pv[3], ov[3];
    float rowsum = 0.f, pmax = -INFINITY;
    #pragma unroll
    for (int k = 0; k < 3; ++k) {
        int c = lane + k * 64;
        bool ok = c < N_CLS;
        pv[k] = ok ? pr[c]   : -INFINITY;
        ov[k] = ok ? orow[c] : 0.f;
        rowsum += ov[k];
        pmax = fmaxf(pmax, pv[k]);
    }
    #pragma unroll
    for (int off = 32; off; off >>= 1) {
        rowsum += __shfl_xor(rowsum, off);
        pmax = fmaxf(pmax, __shfl_xor(pmax, off));
    }
    float sumexp = 0.f;
    #pragma unroll
    for (int k = 0; k < 3; ++k) {
        int c = lane + k * 64;
        if (c < N_CLS) sumexp += __expf(pv[k] - pmax);
    }
    #pragma unroll
    for (int off = 32; off; off >>= 1) sumexp += __shfl_xor(sumexp, off);
    float lse = __logf(sumexp) + pmax;      // logp[c] = pred[c] - lse

    float inv = 1.f / rowsum;
    float ce = 0.f, bestv = -INFINITY;
    int besti = 0;
    #pragma unroll
    for (int k = 0; k < 3; ++k) {
        int c = lane + k * 64;
        if (c >= N_CLS) continue;
        float tg = ov[k] * inv;
        if (c != 0) ce -= tg * (pv[k] - lse);   // cls_w[0] = 0
        if (tg > bestv) { bestv = tg; besti = c; }  // first max within lane
    }
    #pragma unroll
    for (int off = 32; off; off >>= 1) {
        ce += __shfl_xor(ce, off);
        float bv = __shfl_xor(bestv, off);
        int   bi = __shfl_xor(besti, off);
        if (bv > bestv || (bv == bestv && bi < besti)) { bestv = bv; besti = bi; }
    }
    if (lane == 0) {
        float ptv = __expf(pr[besti] - lse);    // softmax at argmax(target)
        float x  = 1.f - ptv;
        float x2 = x * x;
        s_l[threadIdx.x >> 6] = x2 * x2 * ce * cnorm;
    }
    __syncthreads();
    if (threadIdx.x == 0) {
        float s = s_l[0] + s_l[1] + s_l[2] + s_l[3];
        atomicAdd(loss_out, s * (1.0f / (float)N_PRED));
    }
}

// Host-side: reproduce _norm_factor(4.0) — trapezoid of (1-t^5)/(1-t), 1000 pts.
static float compute_cnorm() {
    const double eps = 1e-7, gamma = 4.0;
    double h = 0.0, prev_t = 0.0, prev_y = 1.0;   // y(0) = 1
    for (int i = 1; i < 1000; ++i) {
        double t = (double)i * (1.0 - eps) / 999.0;
        double y = (1.0 - pow(t, gamma + 1.0)) / (1.0 - t);
        h += 0.5 * (y + prev_y) * (t - prev_t);
        prev_t = t; prev_y = y;
    }
    return (float)((gamma + 1.0) / h);
}

extern "C" void kernel_launch(void* const* d_in, const int* in_sizes, int n_in,
                              void* d_out, int out_size, void* d_ws, size_t ws_size,
                              hipStream_t stream) {
    const float* pred      = (const float*)d_in[0];
    const int*   predseg   = (const int*)d_in[1];
    const int*   targetseg = (const int*)d_in[2];

    unsigned char* ws = (unsigned char*)d_ws;
    unsigned short* keys = (unsigned short*)ws;
    unsigned* dir  = (unsigned*)(ws + KEYS_BYTES);
    unsigned* g_nt = (unsigned*)(ws + KEYS_BYTES + DIR_BYTES);
    float*    outb = (float*)  (ws + KEYS_BYTES + DIR_BYTES + NT_BYTES);

    float cnorm = compute_cnorm();

    hipMemsetAsync(g_nt, 0, NT_BYTES, stream);                    // only n_t needs zeroing
    hipMemsetAsync(d_out, 0, sizeof(float) * (size_t)out_size, stream);

    partition_kernel <<<NBLK_A, 256, 0, stream>>>(predseg, targetseg, keys, dir, g_nt);
    hist_sweep_kernel<<<NBUK,   512, 0, stream>>>(keys, dir, g_nt, outb);
    loss_kernel      <<<N_PRED / 4, 256, 0, stream>>>(pred, outb, (float*)d_out, cnorm);
}